// Round 1
// baseline (846.298 us; speedup 1.0000x reference)
//
#include <hip/hip_runtime.h>

typedef _Float16 half8 __attribute__((ext_vector_type(8)));
typedef _Float16 half4 __attribute__((ext_vector_type(4)));
typedef _Float16 half2 __attribute__((ext_vector_type(2)));
typedef float    f32x4 __attribute__((ext_vector_type(4)));
typedef float    f32x2 __attribute__((ext_vector_type(2)));
typedef unsigned u32x2 __attribute__((ext_vector_type(2)));
typedef unsigned u32x4 __attribute__((ext_vector_type(4)));

#define TMASK ((1u << 19) - 1u)       // T = 2^19
#define HSTRIDE 136                    // fallback-kernel LDS stride
constexpr float SCALE = 65536.0f;      // activation scale: keeps f16 out of subnormal range
constexpr float INV_SCALE = 1.0f / 65536.0f;

// Dense-remap geometry, coarse levels 0..7 (s = res+2 guards x=1.0 edge).
// R8: 16B slots of 4 x-consecutive f16x2 entries; sx4 = ceil(s/4) slots/row.
__device__ __constant__ unsigned SC_TAB[8]   = {18, 22, 27, 34, 42, 52, 66, 82};
__device__ __constant__ unsigned SX4_TAB[8]  = {5, 6, 7, 9, 11, 13, 17, 21};
__device__ __constant__ unsigned DOFF16_TAB[8] = {0, 1620, 4524, 9627, 20031, 39435, 74587, 148639};
#define DSLOT_TOTAL 289843u

// ---------------------------------------------------------------------------
// Prep: (a) fp32 FINE tables (levels 8-15) -> f16 pre-scaled, (b) weights ->
// fragment-native f16 layout + biases. (unchanged)
// ---------------------------------------------------------------------------
__global__ void prep_kernel(const float* __restrict__ W0, const float* __restrict__ W1,
                            const float* __restrict__ W2, const float* __restrict__ W3,
                            const float* __restrict__ Wm,
                            const float* __restrict__ b0, const float* __restrict__ b1,
                            const float* __restrict__ b2, const float* __restrict__ b3,
                            const float* __restrict__ bm,
                            _Float16* __restrict__ wsW, float* __restrict__ wsB,
                            const float* __restrict__ tabSrc, _Float16* __restrict__ tabF,
                            int tabBlocks)
{
    if ((int)blockIdx.x < tabBlocks) {
        size_t i = (size_t)blockIdx.x * 256 + threadIdx.x;
        f32x4 v = ((const f32x4*)tabSrc)[i];
        half4 o;
        o[0] = (_Float16)(v.x * SCALE);
        o[1] = (_Float16)(v.y * SCALE);
        o[2] = (_Float16)(v.z * SCALE);
        o[3] = (_Float16)(v.w * SCALE);
        ((half4*)tabF)[i] = o;
        return;
    }
    int gid = ((int)blockIdx.x - tabBlocks) * 256 + threadIdx.x;
    if (gid < 6912) {                       // 108 tiles * 64 lanes
        int tile = gid >> 6, lane = gid & 63;
        const float* W; int K, N, toff;
        if (tile < 8)        { W = W0; K = 32;  N = 128; toff = 0;   }
        else if (tile < 40)  { W = W1; K = 128; N = 128; toff = 8;   }
        else if (tile < 72)  { W = W2; K = 128; N = 128; toff = 40;  }
        else if (tile < 104) { W = W3; K = 128; N = 128; toff = 72;  }
        else                 { W = Wm; K = 128; N = 4;   toff = 104; }
        int tt = tile - toff;
        int KT = K >> 5;
        int nt = tt / KT, kt = tt - nt * KT;
        int n = nt * 16 + (lane & 15);
        int kbase = kt * 32 + (lane >> 4) * 8;
        half8 v;
        #pragma unroll
        for (int j = 0; j < 8; j++) {
            int k = kbase + j;
            float w = (n < N) ? W[k * N + n] : 0.0f;
            v[j] = (_Float16)w;
        }
        *(half8*)(wsW + (size_t)gid * 8) = v;
    } else if (gid < 6912 + 528) {
        int i = gid - 6912;
        float v;
        if (i < 512) {
            int layer = i >> 7, n = i & 127;
            const float* b = (layer == 0) ? b0 : (layer == 1) ? b1 : (layer == 2) ? b2 : b3;
            v = b[n] * SCALE;
        } else {
            int n = i - 512;
            v = (n < 4) ? bm[n] * SCALE : 0.0f;
        }
        wsB[i] = v;
    }
}

// ---------------------------------------------------------------------------
// Dense remap build, 16B-slot layout: slot (x>>2, y, z) holds entries for
// x = 4*(x>>2)+{0..3}; value = f16(table[l][hash(x,y,z) % T]) (bit-identical
// to hashed lookup). Pad entries (x >= s) are never selected.
// One thread per dword (4 per slot).
// ---------------------------------------------------------------------------
__global__ void dense_build(const float* __restrict__ tables, unsigned* __restrict__ dense)
{
    unsigned e = blockIdx.x * 256 + threadIdx.x;
    if (e >= DSLOT_TOTAL * 4u) return;
    unsigned slot = e >> 2, j = e & 3u;
    int l = 0;
    #pragma unroll
    for (int i = 1; i < 8; i++) l += (slot >= DOFF16_TAB[i]) ? 1 : 0;
    unsigned local = slot - DOFF16_TAB[l];
    unsigned s = SC_TAB[l], sx4 = SX4_TAB[l];
    unsigned plane = sx4 * s;
    unsigned z = local / plane;
    unsigned rem = local - z * plane;
    unsigned y = rem / sx4;
    unsigned xs = rem - y * sx4;
    unsigned x = xs * 4u + j;
    unsigned h = (x ^ (y * 2654435761u) ^ (z * 805459861u)) & TMASK;
    const float* src = tables + ((size_t)l * 524288u + h) * 2;
    half2 o; o[0] = (_Float16)(src[0] * SCALE); o[1] = (_Float16)(src[1] * SCALE);
    union { half2 h2; unsigned u; } cv; cv.h2 = o;
    dense[e] = cv.u;
}

// ---------------------------------------------------------------------------
// Encode kernel R9: identical to R8 except occupancy cap lifted 4 -> 8
// waves/EU. VGPR=56 fits the 64-reg/8-wave bin; kernel is latency x
// concurrency bound (5% HBM, 15% VALU, 0 MFMA) so doubling resident waves
// doubles loads in flight. XCD affinity (lvl0 = bid&7) is unaffected by
// blocks/CU, so per-XCD L2 footprint is unchanged.
// ---------------------------------------------------------------------------
__global__ __launch_bounds__(256, 8) void encode_kernel(
    const float* __restrict__ pos, const float* __restrict__ bmn, const float* __restrict__ bmx,
    const _Float16* __restrict__ tabFine, const u32x4* __restrict__ dense16,
    _Float16* __restrict__ feat, int npts)
{
    const int lvl0 = (int)(blockIdx.x & 7);
    const int t = (int)threadIdx.x;
    const long p0 = (long)(blockIdx.x >> 3) * 512 + t;    // second point: p0 + 256
    const float bx = bmn[0], by = bmn[1], bz = bmn[2];
    const float dxr = bmx[0] - bx, dyr = bmx[1] - by, dzr = bmx[2] - bz;
    constexpr float RESL[16] = {16.f, 20.f, 25.f, 32.f, 40.f, 50.f, 64.f, 80.f,
                                101.f, 128.f, 161.f, 203.f, 256.f, 322.f, 406.f, 512.f};
    const int l1 = lvl0 + 8;
    const _Float16* tblB = tabFine + ((size_t)lvl0 << 20);
    const float resF = RESL[l1], resC = RESL[lvl0];
    const unsigned s   = SC_TAB[lvl0];
    const unsigned sx4 = SX4_TAB[lvl0];
    const unsigned plane = sx4 * s;
    const u32x4* dptr = dense16 + DOFF16_TAB[lvl0];

    // ---- per-point state ----
    unsigned fSlot[2][4], fOdd[2][4], cBase[2][4];
    unsigned peM[2], kC[2];
    bool oddF[2], nx3[2];
    float fF[2][3], fC[2][3];   // fracs fine/coarse

    #pragma unroll
    for (int pt = 0; pt < 2; pt++) {
        const long p = p0 + pt * 256;
        const float nx = (pos[p * 3 + 0] - bx) / dxr;
        const float ny = (pos[p * 3 + 1] - by) / dyr;
        const float nz = (pos[p * 3 + 2] - bz) / dzr;
        {   // fine (hashed)
            float xs = nx * resF, ys = ny * resF, zs = nz * resF;
            float fx = floorf(xs), fy = floorf(ys), fz = floorf(zs);
            unsigned xi = (unsigned)fx, yi = (unsigned)fy, zi = (unsigned)fz;
            fF[pt][0] = xs - fx; fF[pt][1] = ys - fy; fF[pt][2] = zs - fz;
            unsigned hy0 = yi * 2654435761u, hy1 = (yi + 1u) * 2654435761u;
            unsigned hz0 = zi * 805459861u,  hz1 = (zi + 1u) * 805459861u;
            unsigned hyz[4] = {hy0 ^ hz0, hy1 ^ hz0, hy0 ^ hz1, hy1 ^ hz1};
            unsigned e = (xi + 1u) & ~1u, o = xi | 1u;
            oddF[pt] = (xi & 1u) != 0u;
            unsigned m = 0;
            #pragma unroll
            for (int g = 0; g < 4; g++) {
                unsigned ie = (e ^ hyz[g]) & TMASK;
                fSlot[pt][g] = ie & ~1u;
                m |= (ie & 1u) << g;
                fOdd[pt][g] = (o ^ hyz[g]) & TMASK;
            }
            peM[pt] = m;
        }
        {   // coarse (dense 16B slots)
            float xs = nx * resC, ys = ny * resC, zs = nz * resC;
            float fx = floorf(xs), fy = floorf(ys), fz = floorf(zs);
            unsigned xi = (unsigned)fx, yi = (unsigned)fy, zi = (unsigned)fz;
            fC[pt][0] = xs - fx; fC[pt][1] = ys - fy; fC[pt][2] = zs - fz;
            unsigned b00 = (xi >> 2) + sx4 * yi + plane * zi;
            cBase[pt][0] = b00;
            cBase[pt][1] = b00 + sx4;
            cBase[pt][2] = b00 + plane;
            cBase[pt][3] = b00 + plane + sx4;
            kC[pt] = xi & 3u;
            nx3[pt] = (kC[pt] == 3u);
        }
    }

    // ---- issue loads: p0 batch then p1 batch ----
    u32x2 fS[2][4]; u32x4 cS[2][4]; unsigned fO[2][4], cN[2][4];
    #pragma unroll
    for (int pt = 0; pt < 2; pt++) {
        #pragma unroll
        for (int g = 0; g < 4; g++)
            fS[pt][g] = *(const u32x2*)(tblB + (size_t)fSlot[pt][g] * 2);
        #pragma unroll
        for (int g = 0; g < 4; g++)
            cS[pt][g] = dptr[cBase[pt][g]];
        if (oddF[pt]) {
            #pragma unroll
            for (int g = 0; g < 4; g++)
                fO[pt][g] = *(const unsigned*)(tblB + (size_t)fOdd[pt][g] * 2);
        }
        if (nx3[pt]) {
            #pragma unroll
            for (int g = 0; g < 4; g++)
                cN[pt][g] = *(const unsigned*)(dptr + cBase[pt][g] + 1);
        }
    }

    // ---- consume p0 then p1 (p1 loads remain outstanding during p0) ----
    #pragma unroll
    for (int pt = 0; pt < 2; pt++) {
        const long p = p0 + pt * 256;
        {   // fine
            float tx = fF[pt][0], ty = fF[pt][1], tz = fF[pt][2];
            float wyz[4] = {(1.0f - ty) * (1.0f - tz), ty * (1.0f - tz),
                            (1.0f - ty) * tz,          ty * tz};
            float b0 = 0.0f, b1 = 0.0f;
            #pragma unroll
            for (int g = 0; g < 4; g++) {
                union { unsigned u; half2 h; } lo, hi, ov;
                lo.u = fS[pt][g][0]; hi.u = fS[pt][g][1];
                bool pe = ((peM[pt] >> g) & 1u) != 0u;
                half2 fe  = pe ? hi.h : lo.h;
                half2 fe1 = pe ? lo.h : hi.h;
                ov.u = oddF[pt] ? fO[pt][g] : 0u;
                half2 fx0 = oddF[pt] ? ov.h : fe;
                half2 fx1 = oddF[pt] ? fe : fe1;
                float w0 = wyz[g] * (1.0f - tx), w1 = wyz[g] * tx;
                b0 += w0 * (float)fx0[0] + w1 * (float)fx1[0];
                b1 += w0 * (float)fx0[1] + w1 * (float)fx1[1];
            }
            half2 ov2; ov2[0] = (_Float16)b0; ov2[1] = (_Float16)b1;
            union { half2 h; unsigned u; } cv; cv.h = ov2;
            __builtin_nontemporal_store(cv.u, (unsigned*)(feat + ((size_t)l1 * npts + p) * 2));
        }
        {   // coarse
            float tx = fC[pt][0], ty = fC[pt][1], tz = fC[pt][2];
            float wyz[4] = {(1.0f - ty) * (1.0f - tz), ty * (1.0f - tz),
                            (1.0f - ty) * tz,          ty * tz};
            unsigned k = kC[pt];
            unsigned kp1 = (k < 3u) ? (k + 1u) : 0u;
            float a0 = 0.0f, a1 = 0.0f;
            #pragma unroll
            for (int g = 0; g < 4; g++) {
                union { unsigned u; half2 h; } u0, u1;
                u0.u = cS[pt][g][k];
                u1.u = nx3[pt] ? cN[pt][g] : cS[pt][g][kp1];
                float w0 = wyz[g] * (1.0f - tx), w1 = wyz[g] * tx;
                a0 += w0 * (float)u0.h[0] + w1 * (float)u1.h[0];
                a1 += w0 * (float)u0.h[1] + w1 * (float)u1.h[1];
            }
            half2 ov2; ov2[0] = (_Float16)a0; ov2[1] = (_Float16)a1;
            union { half2 h; unsigned u; } cv; cv.h = ov2;
            __builtin_nontemporal_store(cv.u, (unsigned*)(feat + ((size_t)lvl0 * npts + p) * 2));
        }
    }
}

// ---------------------------------------------------------------------------
// MLP kernel (R7, unchanged): role-swapped MFMA, 64 points/wave, per-mt
// publish, b128 exchange, wave-private, NO barriers.
// ---------------------------------------------------------------------------
#define ELANE 68   // dwords per lane: 64 payload + 4 pad; 272B (16B-aligned)

template<int KT, int TOFF>
__device__ __forceinline__ void layer_fwd4(half8 b[4][4], const half8* __restrict__ wf,
                                           const float* __restrict__ wsB, int li,
                                           unsigned* __restrict__ eb, int lane, int quad,
                                           unsigned srcA, unsigned srcB, int mtbase)
{
    unsigned* wptr = eb + lane * ELANE;
    #pragma unroll
    for (int mt = 0; mt < 8; mt++) {
        f32x4 bias = *(const f32x4*)&wsB[li * 128 + mt * 16 + quad * 4];
        half8 w[KT];
        #pragma unroll
        for (int kt = 0; kt < KT; kt++)
            w[kt] = wf[(size_t)(TOFF + mt * KT + kt) * 64 + lane];
        f32x4 acc[4] = {bias, bias, bias, bias};
        #pragma unroll
        for (int nt = 0; nt < 4; nt++)
            #pragma unroll
            for (int kt = 0; kt < KT; kt++)
                acc[nt] = __builtin_amdgcn_mfma_f32_16x16x32_f16(w[kt], b[nt][kt], acc[nt], 0, 0, 0);
        #pragma unroll
        for (int np = 0; np < 2; np++) {
            union { _Float16 h[8]; u32x4 v; } pk;
            #pragma unroll
            for (int r = 0; r < 4; r++) {
                pk.h[r]     = (_Float16)fmaxf(acc[2 * np][r],     0.0f);
                pk.h[4 + r] = (_Float16)fmaxf(acc[2 * np + 1][r], 0.0f);
            }
            *(u32x4*)(wptr + mt * 8 + np * 4) = pk.v;
        }
    }
    #pragma unroll
    for (int ktp = 0; ktp < 4; ktp++) {
        int mt = 2 * ktp + mtbase;
        u32x4 rA0 = *(const u32x4*)(eb + srcA * ELANE + mt * 8);
        u32x4 rA1 = *(const u32x4*)(eb + srcA * ELANE + mt * 8 + 4);
        u32x4 rB0 = *(const u32x4*)(eb + srcB * ELANE + mt * 8);
        u32x4 rB1 = *(const u32x4*)(eb + srcB * ELANE + mt * 8 + 4);
        union { u32x4 v; half8 h; } c0, c1, c2, c3;
        c0.v = (u32x4){rA0[0], rA0[1], rB0[0], rB0[1]};
        c1.v = (u32x4){rA0[2], rA0[3], rB0[2], rB0[3]};
        c2.v = (u32x4){rA1[0], rA1[1], rB1[0], rB1[1]};
        c3.v = (u32x4){rA1[2], rA1[3], rB1[2], rB1[3]};
        b[0][ktp] = c0.h;
        b[1][ktp] = c1.h;
        b[2][ktp] = c2.h;
        b[3][ktp] = c3.h;
    }
}

__global__ __launch_bounds__(256) void mlp_kernel(
    const unsigned* __restrict__ feat32, const half8* __restrict__ wf,
    const float* __restrict__ wsB, float* __restrict__ out, int npts)
{
    __shared__ __align__(16) unsigned ebuf[4 * 64 * ELANE];
    const int t = threadIdx.x;
    const int lane = t & 63, wv = t >> 6;
    const int col = lane & 15, quad = lane >> 4;
    const long base = (long)blockIdx.x * 256 + wv * 64;
    unsigned* eb = ebuf + wv * (64 * ELANE);
    const int q1 = 2 * (quad & 1);
    const unsigned srcA = (unsigned)(col + 16 * q1);
    const unsigned srcB = (unsigned)(col + 16 * (q1 + 1));
    const int mtbase = quad >> 1;

    half8 b[4][4];
    #pragma unroll
    for (int nt = 0; nt < 4; nt++) {
        const long pt = base + nt * 16 + col;
        union { unsigned u4[4]; half8 v; } cv;
        #pragma unroll
        for (int jj = 0; jj < 4; jj++)
            cv.u4[jj] = feat32[(size_t)(quad * 4 + jj) * npts + pt];
        b[nt][0] = cv.v;
    }

    layer_fwd4<1, 0 >(b, wf, wsB, 0, eb, lane, quad, srcA, srcB, mtbase);  // 32->128
    layer_fwd4<4, 8 >(b, wf, wsB, 1, eb, lane, quad, srcA, srcB, mtbase);  // 128->128
    layer_fwd4<4, 40>(b, wf, wsB, 2, eb, lane, quad, srcA, srcB, mtbase);  // 128->128
    layer_fwd4<4, 72>(b, wf, wsB, 3, eb, lane, quad, srcA, srcB, mtbase);  // 128->128

    f32x4 biaso = *(const f32x4*)&wsB[512 + quad * 4];
    f32x4 acco[4] = {biaso, biaso, biaso, biaso};
    #pragma unroll
    for (int kt = 0; kt < 4; kt++) {
        half8 w = wf[(size_t)(104 + kt) * 64 + lane];
        #pragma unroll
        for (int nt = 0; nt < 4; nt++)
            acco[nt] = __builtin_amdgcn_mfma_f32_16x16x32_f16(w, b[nt][kt], acco[nt], 0, 0, 0);
    }
    if (quad == 0) {
        #pragma unroll
        for (int nt = 0; nt < 4; nt++) {
            f32x4 v;
            #pragma unroll
            for (int r = 0; r < 4; r++) v[r] = acco[nt][r] * INV_SCALE;
            *(f32x4*)(out + (base + nt * 16 + col) * 4) = v;
        }
    }
}

// ---------------------------------------------------------------------------
// Fallback path (ws too small): R1-style fused kernel, unchanged.
// ---------------------------------------------------------------------------
template<int KT, int TOFF, bool RELU>
__device__ __forceinline__ void mlp_layer(_Float16* h, const half8* __restrict__ wf,
                                          const float* __restrict__ wsB, int layerIdx,
                                          int m0, int lane)
{
    const int col = lane & 15, quad = lane >> 4;
    const int sw = (col & 3) << 3;
    half8 a[2][KT];
    #pragma unroll
    for (int mt = 0; mt < 2; mt++)
        #pragma unroll
        for (int kt = 0; kt < KT; kt++)
            a[mt][kt] = *(const half8*)&h[(m0 + mt * 16 + col) * HSTRIDE + ((kt * 32 + quad * 8) ^ sw)];
    f32x4 acc[2][8];
    #pragma unroll
    for (int nt = 0; nt < 8; nt++) {
        float bv = wsB[layerIdx * 128 + nt * 16 + col];
        acc[0][nt] = (f32x4){bv, bv, bv, bv};
        acc[1][nt] = (f32x4){bv, bv, bv, bv};
    }
    #pragma unroll
    for (int nt = 0; nt < 8; nt++) {
        half8 b[KT];
        #pragma unroll
        for (int kt = 0; kt < KT; kt++)
            b[kt] = wf[(size_t)(TOFF + nt * KT + kt) * 64 + lane];
        #pragma unroll
        for (int mt = 0; mt < 2; mt++)
            #pragma unroll
            for (int kt = 0; kt < KT; kt++)
                acc[mt][nt] = __builtin_amdgcn_mfma_f32_16x16x32_f16(a[mt][kt], b[kt], acc[mt][nt], 0, 0, 0);
    }
    #pragma unroll
    for (int mt = 0; mt < 2; mt++)
        #pragma unroll
        for (int nt = 0; nt < 8; nt++) {
            f32x4 v = acc[mt][nt];
            #pragma unroll
            for (int r = 0; r < 4; r++) {
                float x = v[r];
                if (RELU) x = fmaxf(x, 0.0f);
                h[(m0 + mt * 16 + quad * 4 + r) * HSTRIDE + ((nt * 16 + col) ^ (r << 3))] = (_Float16)x;
            }
        }
}

__global__ __launch_bounds__(256, 2) void fused_kernel(
    const float* __restrict__ pos, const float* __restrict__ bmn, const float* __restrict__ bmx,
    const float* __restrict__ tables, const half8* __restrict__ wf, const float* __restrict__ wsB,
    float* __restrict__ out)
{
    __shared__ _Float16 hbuf[128 * HSTRIDE];
    __shared__ float outstage[512];
    const int t = threadIdx.x;
    const long base = (long)blockIdx.x * 128;
    {
        const int p = t >> 1, hh = t & 1;
        const long gp = base + p;
        const float b0x = bmn[0], b0y = bmn[1], b0z = bmn[2];
        const float nx = (pos[gp * 3 + 0] - b0x) / (bmx[0] - b0x);
        const float ny = (pos[gp * 3 + 1] - b0y) / (bmx[1] - b0y);
        const float nz = (pos[gp * 3 + 2] - b0z) / (bmx[2] - b0z);
        constexpr float RLO[8] = {16.f, 20.f, 25.f, 32.f, 40.f, 50.f, 64.f, 80.f};
        constexpr float RHI[8] = {101.f, 128.f, 161.f, 203.f, 256.f, 322.f, 406.f, 512.f};
        half8 fa, fb;
        #pragma unroll
        for (int li = 0; li < 8; li++) {
            const float res = hh ? RHI[li] : RLO[li];
            const float* tbl = tables + ((size_t)(hh * 8 + li) << 20);
            float xs = nx * res, ys = ny * res, zs = nz * res;
            float fx = floorf(xs), fy = floorf(ys), fz = floorf(zs);
            unsigned xi = (unsigned)fx, yi = (unsigned)fy, zi = (unsigned)fz;
            float tx = xs - fx, ty = ys - fy, tz = zs - fz;
            unsigned hx[2] = {xi, xi + 1u};
            unsigned hy[2] = {yi * 2654435761u, (yi + 1u) * 2654435761u};
            unsigned hz[2] = {zi * 805459861u, (zi + 1u) * 805459861u};
            float wx[2] = {1.0f - tx, tx}, wy[2] = {1.0f - ty, ty}, wz[2] = {1.0f - tz, tz};
            float a0 = 0.0f, a1 = 0.0f;
            #pragma unroll
            for (int c = 0; c < 8; c++) {
                unsigned hsh = hx[c & 1] ^ hy[(c >> 1) & 1] ^ hz[c >> 2];
                unsigned idx = hsh & TMASK;
                f32x2 f = *(const f32x2*)(tbl + (size_t)idx * 2);
                float w = wx[c & 1] * wy[(c >> 1) & 1] * wz[c >> 2];
                a0 += w * f.x;
                a1 += w * f.y;
            }
            if (li < 4) { fa[2 * li]       = (_Float16)(a0 * SCALE); fa[2 * li + 1]       = (_Float16)(a1 * SCALE); }
            else        { fb[2 * (li - 4)] = (_Float16)(a0 * SCALE); fb[2 * (li - 4) + 1] = (_Float16)(a1 * SCALE); }
        }
        const int sw = (p & 3) << 3;
        *(half8*)&hbuf[p * HSTRIDE + ((hh * 16) ^ sw)]       = fa;
        *(half8*)&hbuf[p * HSTRIDE + (((hh * 16) + 8) ^ sw)] = fb;
    }
    __syncthreads();
    {
        const int lane = t & 63;
        const int m0 = (t >> 6) * 32;
        mlp_layer<1, 0,   true>(hbuf, wf, wsB, 0, m0, lane);
        mlp_layer<4, 8,   true>(hbuf, wf, wsB, 1, m0, lane);
        mlp_layer<4, 40,  true>(hbuf, wf, wsB, 2, m0, lane);
        mlp_layer<4, 72,  true>(hbuf, wf, wsB, 3, m0, lane);
        const int col = lane & 15, quad = lane >> 4;
        const int sw = (col & 3) << 3;
        half8 a[2][4];
        #pragma unroll
        for (int mt = 0; mt < 2; mt++)
            #pragma unroll
            for (int kt = 0; kt < 4; kt++)
                a[mt][kt] = *(const half8*)&hbuf[(m0 + mt * 16 + col) * HSTRIDE + ((kt * 32 + quad * 8) ^ sw)];
        float bv = wsB[512 + col];
        f32x4 acc[2] = {(f32x4){bv, bv, bv, bv}, (f32x4){bv, bv, bv, bv}};
        #pragma unroll
        for (int kt = 0; kt < 4; kt++) {
            half8 bfr = wf[(size_t)(104 + kt) * 64 + lane];
            #pragma unroll
            for (int mt = 0; mt < 2; mt++)
                acc[mt] = __builtin_amdgcn_mfma_f32_16x16x32_f16(a[mt][kt], bfr, acc[mt], 0, 0, 0);
        }
        if (col < 4) {
            #pragma unroll
            for (int mt = 0; mt < 2; mt++)
                #pragma unroll
                for (int r = 0; r < 4; r++)
                    outstage[(m0 + mt * 16 + quad * 4 + r) * 4 + col] = acc[mt][r] * INV_SCALE;
        }
    }
    __syncthreads();
    if (t < 128) {
        f32x4 v = ((const f32x4*)outstage)[t];
        *(f32x4*)(out + (base + t) * 4) = v;
    }
}

extern "C" void kernel_launch(void* const* d_in, const int* in_sizes, int n_in,
                              void* d_out, int out_size, void* d_ws, size_t ws_size,
                              hipStream_t stream) {
    const float* pos    = (const float*)d_in[0];
    const float* bmn    = (const float*)d_in[1];
    const float* bmx    = (const float*)d_in[2];
    const float* tables = (const float*)d_in[3];
    const float* W0 = (const float*)d_in[4];
    const float* b0 = (const float*)d_in[5];
    const float* W1 = (const float*)d_in[6];
    const float* b1 = (const float*)d_in[7];
    const float* W2 = (const float*)d_in[8];
    const float* b2 = (const float*)d_in[9];
    const float* W3 = (const float*)d_in[10];
    const float* b3 = (const float*)d_in[11];
    const float* Wm = (const float*)d_in[12];
    const float* bm = (const float*)d_in[13];

    const int N = in_sizes[0] / 3;
    const size_t featBytes    = (size_t)N * 16 * 4;             // [16][N] f16x2
    const size_t tabFineBytes = (size_t)8 * 524288 * 2 * 2;     // 16 MB f16, levels 8-15
    const size_t denseBytes   = ((size_t)DSLOT_TOTAL * 16 + 255) & ~(size_t)255;  // ~4.6 MB
    const size_t need = featBytes + tabFineBytes + denseBytes + 110592 + 2112;

    if (ws_size >= need && (N % 512) == 0) {
        _Float16* feat  = (_Float16*)d_ws;
        _Float16* tabF  = (_Float16*)((char*)d_ws + featBytes);
        unsigned* dense = (unsigned*)((char*)d_ws + featBytes + tabFineBytes);
        _Float16* wsW   = (_Float16*)((char*)d_ws + featBytes + tabFineBytes + denseBytes);
        float*    wsB   = (float*)((char*)d_ws + featBytes + tabFineBytes + denseBytes + 110592);
        prep_kernel<<<8192 + 30, 256, 0, stream>>>(W0, W1, W2, W3, Wm, b0, b1, b2, b3, bm,
                                                   wsW, wsB, tables + (size_t)8 * 524288 * 2,
                                                   tabF, 8192);
        dense_build<<<(DSLOT_TOTAL * 4 + 255) / 256, 256, 0, stream>>>(tables, dense);
        encode_kernel<<<(N / 512) * 8, 256, 0, stream>>>(pos, bmn, bmx, tabF,
                                                         (const u32x4*)dense, feat, N);
        mlp_kernel<<<N / 256, 256, 0, stream>>>((const unsigned*)feat, (const half8*)wsW,
                                                wsB, (float*)d_out, N);
    } else {
        _Float16* wsW = (_Float16*)d_ws;
        float*    wsB = (float*)((char*)d_ws + 110592);
        prep_kernel<<<30, 256, 0, stream>>>(W0, W1, W2, W3, Wm, b0, b1, b2, b3, bm,
                                            wsW, wsB, tables, (_Float16*)nullptr, 0);
        fused_kernel<<<N / 128, 256, 0, stream>>>(pos, bmn, bmx, tables,
                                                  (const half8*)wsW, wsB, (float*)d_out);
    }
}

// Round 2
// 617.747 us; speedup vs baseline: 1.3700x; 1.3700x over previous
//
#include <hip/hip_runtime.h>

typedef _Float16 half8 __attribute__((ext_vector_type(8)));
typedef _Float16 half4 __attribute__((ext_vector_type(4)));
typedef _Float16 half2 __attribute__((ext_vector_type(2)));
typedef float    f32x4 __attribute__((ext_vector_type(4)));
typedef float    f32x2 __attribute__((ext_vector_type(2)));
typedef unsigned u32x2 __attribute__((ext_vector_type(2)));
typedef unsigned u32x4 __attribute__((ext_vector_type(4)));

#define TMASK ((1u << 19) - 1u)       // T = 2^19
#define HSTRIDE 136                    // fallback-kernel LDS stride
constexpr float SCALE = 65536.0f;      // activation scale: keeps f16 out of subnormal range
constexpr float INV_SCALE = 1.0f / 65536.0f;

// Dense-remap geometry, coarse levels 0..7 (s = res+2 guards x=1.0 edge).
// R8: 16B slots of 4 x-consecutive f16x2 entries; sx4 = ceil(s/4) slots/row.
__device__ __constant__ unsigned SC_TAB[8]   = {18, 22, 27, 34, 42, 52, 66, 82};
__device__ __constant__ unsigned SX4_TAB[8]  = {5, 6, 7, 9, 11, 13, 17, 21};
__device__ __constant__ unsigned DOFF16_TAB[8] = {0, 1620, 4524, 9627, 20031, 39435, 74587, 148639};
#define DSLOT_TOTAL 289843u

// ---------------------------------------------------------------------------
// Prep: (a) fp32 FINE tables (levels 8-15) -> f16 pre-scaled, (b) weights ->
// fragment-native f16 layout + biases. (unchanged)
// ---------------------------------------------------------------------------
__global__ void prep_kernel(const float* __restrict__ W0, const float* __restrict__ W1,
                            const float* __restrict__ W2, const float* __restrict__ W3,
                            const float* __restrict__ Wm,
                            const float* __restrict__ b0, const float* __restrict__ b1,
                            const float* __restrict__ b2, const float* __restrict__ b3,
                            const float* __restrict__ bm,
                            _Float16* __restrict__ wsW, float* __restrict__ wsB,
                            const float* __restrict__ tabSrc, _Float16* __restrict__ tabF,
                            int tabBlocks)
{
    if ((int)blockIdx.x < tabBlocks) {
        size_t i = (size_t)blockIdx.x * 256 + threadIdx.x;
        f32x4 v = ((const f32x4*)tabSrc)[i];
        half4 o;
        o[0] = (_Float16)(v.x * SCALE);
        o[1] = (_Float16)(v.y * SCALE);
        o[2] = (_Float16)(v.z * SCALE);
        o[3] = (_Float16)(v.w * SCALE);
        ((half4*)tabF)[i] = o;
        return;
    }
    int gid = ((int)blockIdx.x - tabBlocks) * 256 + threadIdx.x;
    if (gid < 6912) {                       // 108 tiles * 64 lanes
        int tile = gid >> 6, lane = gid & 63;
        const float* W; int K, N, toff;
        if (tile < 8)        { W = W0; K = 32;  N = 128; toff = 0;   }
        else if (tile < 40)  { W = W1; K = 128; N = 128; toff = 8;   }
        else if (tile < 72)  { W = W2; K = 128; N = 128; toff = 40;  }
        else if (tile < 104) { W = W3; K = 128; N = 128; toff = 72;  }
        else                 { W = Wm; K = 128; N = 4;   toff = 104; }
        int tt = tile - toff;
        int KT = K >> 5;
        int nt = tt / KT, kt = tt - nt * KT;
        int n = nt * 16 + (lane & 15);
        int kbase = kt * 32 + (lane >> 4) * 8;
        half8 v;
        #pragma unroll
        for (int j = 0; j < 8; j++) {
            int k = kbase + j;
            float w = (n < N) ? W[k * N + n] : 0.0f;
            v[j] = (_Float16)w;
        }
        *(half8*)(wsW + (size_t)gid * 8) = v;
    } else if (gid < 6912 + 528) {
        int i = gid - 6912;
        float v;
        if (i < 512) {
            int layer = i >> 7, n = i & 127;
            const float* b = (layer == 0) ? b0 : (layer == 1) ? b1 : (layer == 2) ? b2 : b3;
            v = b[n] * SCALE;
        } else {
            int n = i - 512;
            v = (n < 4) ? bm[n] * SCALE : 0.0f;
        }
        wsB[i] = v;
    }
}

// ---------------------------------------------------------------------------
// Dense remap build, 16B-slot layout (unchanged).
// ---------------------------------------------------------------------------
__global__ void dense_build(const float* __restrict__ tables, unsigned* __restrict__ dense)
{
    unsigned e = blockIdx.x * 256 + threadIdx.x;
    if (e >= DSLOT_TOTAL * 4u) return;
    unsigned slot = e >> 2, j = e & 3u;
    int l = 0;
    #pragma unroll
    for (int i = 1; i < 8; i++) l += (slot >= DOFF16_TAB[i]) ? 1 : 0;
    unsigned local = slot - DOFF16_TAB[l];
    unsigned s = SC_TAB[l], sx4 = SX4_TAB[l];
    unsigned plane = sx4 * s;
    unsigned z = local / plane;
    unsigned rem = local - z * plane;
    unsigned y = rem / sx4;
    unsigned xs = rem - y * sx4;
    unsigned x = xs * 4u + j;
    unsigned h = (x ^ (y * 2654435761u) ^ (z * 805459861u)) & TMASK;
    const float* src = tables + ((size_t)l * 524288u + h) * 2;
    half2 o; o[0] = (_Float16)(src[0] * SCALE); o[1] = (_Float16)(src[1] * SCALE);
    union { half2 h2; unsigned u; } cv; cv.h2 = o;
    dense[e] = cv.u;
}

// ---------------------------------------------------------------------------
// Encode kernel R10: launch bounds reverted to (256,4) [R9's min=8 forced
// VGPR 56->32 and 1.9 GB of scratch spills — clang's budget is ~256/min_waves].
// Single change vs R0: each thread processes 8 points in a fully-unrolled
// software-pipelined loop with 1-point lookahead (consume p_i while p_{i+1}
// is in flight, then compute+issue p_{i+2}). Live window = 2 points at all
// times — identical register footprint to the proven 56-VGPR R0 schedule —
// but the cold-start (kernarg loads, addr calc, first naked stall) is paid
// once per 8 points instead of once per 2. Grid shrinks 4x.
// ---------------------------------------------------------------------------
struct PtState {
    unsigned fSlot[4], fOdd[4], cBase[4];
    unsigned peM, kC;
    bool oddF, nx3;
    float fF[3], fC[3];
};
struct PtLoads {
    u32x2 fS[4]; u32x4 cS[4]; unsigned fO[4], cN[4];
};

__global__ __launch_bounds__(256, 4) void encode_kernel(
    const float* __restrict__ pos, const float* __restrict__ bmn, const float* __restrict__ bmx,
    const _Float16* __restrict__ tabFine, const u32x4* __restrict__ dense16,
    _Float16* __restrict__ feat, int npts)
{
    const int lvl0 = (int)(blockIdx.x & 7);
    const int t = (int)threadIdx.x;
    const long pb = (long)(blockIdx.x >> 3) * 2048 + t;   // points pb + k*256, k=0..7
    const float bx = bmn[0], by = bmn[1], bz = bmn[2];
    const float dxr = bmx[0] - bx, dyr = bmx[1] - by, dzr = bmx[2] - bz;
    constexpr float RESL[16] = {16.f, 20.f, 25.f, 32.f, 40.f, 50.f, 64.f, 80.f,
                                101.f, 128.f, 161.f, 203.f, 256.f, 322.f, 406.f, 512.f};
    const int l1 = lvl0 + 8;
    const _Float16* tblB = tabFine + ((size_t)lvl0 << 20);
    const float resF = RESL[l1], resC = RESL[lvl0];
    const unsigned sx4 = SX4_TAB[lvl0];
    const unsigned plane = sx4 * SC_TAB[lvl0];
    const u32x4* dptr = dense16 + DOFF16_TAB[lvl0];

    auto computePt = [&](long p, PtState& S) {
        const float nx = (pos[p * 3 + 0] - bx) / dxr;
        const float ny = (pos[p * 3 + 1] - by) / dyr;
        const float nz = (pos[p * 3 + 2] - bz) / dzr;
        {   // fine (hashed)
            float xs = nx * resF, ys = ny * resF, zs = nz * resF;
            float fx = floorf(xs), fy = floorf(ys), fz = floorf(zs);
            unsigned xi = (unsigned)fx, yi = (unsigned)fy, zi = (unsigned)fz;
            S.fF[0] = xs - fx; S.fF[1] = ys - fy; S.fF[2] = zs - fz;
            unsigned hy0 = yi * 2654435761u, hy1 = (yi + 1u) * 2654435761u;
            unsigned hz0 = zi * 805459861u,  hz1 = (zi + 1u) * 805459861u;
            unsigned hyz[4] = {hy0 ^ hz0, hy1 ^ hz0, hy0 ^ hz1, hy1 ^ hz1};
            unsigned e = (xi + 1u) & ~1u, o = xi | 1u;
            S.oddF = (xi & 1u) != 0u;
            unsigned m = 0;
            #pragma unroll
            for (int g = 0; g < 4; g++) {
                unsigned ie = (e ^ hyz[g]) & TMASK;
                S.fSlot[g] = ie & ~1u;
                m |= (ie & 1u) << g;
                S.fOdd[g] = (o ^ hyz[g]) & TMASK;
            }
            S.peM = m;
        }
        {   // coarse (dense 16B slots)
            float xs = nx * resC, ys = ny * resC, zs = nz * resC;
            float fx = floorf(xs), fy = floorf(ys), fz = floorf(zs);
            unsigned xi = (unsigned)fx, yi = (unsigned)fy, zi = (unsigned)fz;
            S.fC[0] = xs - fx; S.fC[1] = ys - fy; S.fC[2] = zs - fz;
            unsigned b00 = (xi >> 2) + sx4 * yi + plane * zi;
            S.cBase[0] = b00;
            S.cBase[1] = b00 + sx4;
            S.cBase[2] = b00 + plane;
            S.cBase[3] = b00 + plane + sx4;
            S.kC = xi & 3u;
            S.nx3 = (S.kC == 3u);
        }
    };

    auto issuePt = [&](const PtState& S, PtLoads& L) {
        #pragma unroll
        for (int g = 0; g < 4; g++)
            L.fS[g] = *(const u32x2*)(tblB + (size_t)S.fSlot[g] * 2);
        #pragma unroll
        for (int g = 0; g < 4; g++)
            L.cS[g] = dptr[S.cBase[g]];
        if (S.oddF) {
            #pragma unroll
            for (int g = 0; g < 4; g++)
                L.fO[g] = *(const unsigned*)(tblB + (size_t)S.fOdd[g] * 2);
        }
        if (S.nx3) {
            #pragma unroll
            for (int g = 0; g < 4; g++)
                L.cN[g] = *(const unsigned*)(dptr + S.cBase[g] + 1);
        }
    };

    auto consumePt = [&](const PtState& S, const PtLoads& L, long p) {
        {   // fine
            float tx = S.fF[0], ty = S.fF[1], tz = S.fF[2];
            float wyz[4] = {(1.0f - ty) * (1.0f - tz), ty * (1.0f - tz),
                            (1.0f - ty) * tz,          ty * tz};
            float b0 = 0.0f, b1 = 0.0f;
            #pragma unroll
            for (int g = 0; g < 4; g++) {
                union { unsigned u; half2 h; } lo, hi, ov;
                lo.u = L.fS[g][0]; hi.u = L.fS[g][1];
                bool pe = ((S.peM >> g) & 1u) != 0u;
                half2 fe  = pe ? hi.h : lo.h;
                half2 fe1 = pe ? lo.h : hi.h;
                ov.u = S.oddF ? L.fO[g] : 0u;
                half2 fx0 = S.oddF ? ov.h : fe;
                half2 fx1 = S.oddF ? fe : fe1;
                float w0 = wyz[g] * (1.0f - tx), w1 = wyz[g] * tx;
                b0 += w0 * (float)fx0[0] + w1 * (float)fx1[0];
                b1 += w0 * (float)fx0[1] + w1 * (float)fx1[1];
            }
            half2 ov2; ov2[0] = (_Float16)b0; ov2[1] = (_Float16)b1;
            union { half2 h; unsigned u; } cv; cv.h = ov2;
            __builtin_nontemporal_store(cv.u, (unsigned*)(feat + ((size_t)l1 * npts + p) * 2));
        }
        {   // coarse
            float tx = S.fC[0], ty = S.fC[1], tz = S.fC[2];
            float wyz[4] = {(1.0f - ty) * (1.0f - tz), ty * (1.0f - tz),
                            (1.0f - ty) * tz,          ty * tz};
            unsigned k = S.kC;
            unsigned kp1 = (k < 3u) ? (k + 1u) : 0u;
            float a0 = 0.0f, a1 = 0.0f;
            #pragma unroll
            for (int g = 0; g < 4; g++) {
                union { unsigned u; half2 h; } u0, u1;
                u0.u = L.cS[g][k];
                u1.u = S.nx3 ? L.cN[g] : L.cS[g][kp1];
                float w0 = wyz[g] * (1.0f - tx), w1 = wyz[g] * tx;
                a0 += w0 * (float)u0.h[0] + w1 * (float)u1.h[0];
                a1 += w0 * (float)u0.h[1] + w1 * (float)u1.h[1];
            }
            half2 ov2; ov2[0] = (_Float16)a0; ov2[1] = (_Float16)a1;
            union { half2 h; unsigned u; } cv; cv.h = ov2;
            __builtin_nontemporal_store(cv.u, (unsigned*)(feat + ((size_t)lvl0 * npts + p) * 2));
        }
    };

    // ---- software pipeline: window = 2 points (1 consuming + 1 in flight) ----
    PtState sA, sB; PtLoads lA, lB;
    computePt(pb + 0 * 256, sA); issuePt(sA, lA);
    computePt(pb + 1 * 256, sB); issuePt(sB, lB);
    #pragma unroll
    for (int k = 0; k < 6; k++) {
        if ((k & 1) == 0) {
            consumePt(sA, lA, pb + (long)k * 256);
            computePt(pb + (long)(k + 2) * 256, sA); issuePt(sA, lA);
        } else {
            consumePt(sB, lB, pb + (long)k * 256);
            computePt(pb + (long)(k + 2) * 256, sB); issuePt(sB, lB);
        }
    }
    consumePt(sA, lA, pb + 6 * 256);
    consumePt(sB, lB, pb + 7 * 256);
}

// ---------------------------------------------------------------------------
// MLP kernel (R7, unchanged): role-swapped MFMA, 64 points/wave, per-mt
// publish, b128 exchange, wave-private, NO barriers.
// ---------------------------------------------------------------------------
#define ELANE 68   // dwords per lane: 64 payload + 4 pad; 272B (16B-aligned)

template<int KT, int TOFF>
__device__ __forceinline__ void layer_fwd4(half8 b[4][4], const half8* __restrict__ wf,
                                           const float* __restrict__ wsB, int li,
                                           unsigned* __restrict__ eb, int lane, int quad,
                                           unsigned srcA, unsigned srcB, int mtbase)
{
    unsigned* wptr = eb + lane * ELANE;
    #pragma unroll
    for (int mt = 0; mt < 8; mt++) {
        f32x4 bias = *(const f32x4*)&wsB[li * 128 + mt * 16 + quad * 4];
        half8 w[KT];
        #pragma unroll
        for (int kt = 0; kt < KT; kt++)
            w[kt] = wf[(size_t)(TOFF + mt * KT + kt) * 64 + lane];
        f32x4 acc[4] = {bias, bias, bias, bias};
        #pragma unroll
        for (int nt = 0; nt < 4; nt++)
            #pragma unroll
            for (int kt = 0; kt < KT; kt++)
                acc[nt] = __builtin_amdgcn_mfma_f32_16x16x32_f16(w[kt], b[nt][kt], acc[nt], 0, 0, 0);
        #pragma unroll
        for (int np = 0; np < 2; np++) {
            union { _Float16 h[8]; u32x4 v; } pk;
            #pragma unroll
            for (int r = 0; r < 4; r++) {
                pk.h[r]     = (_Float16)fmaxf(acc[2 * np][r],     0.0f);
                pk.h[4 + r] = (_Float16)fmaxf(acc[2 * np + 1][r], 0.0f);
            }
            *(u32x4*)(wptr + mt * 8 + np * 4) = pk.v;
        }
    }
    #pragma unroll
    for (int ktp = 0; ktp < 4; ktp++) {
        int mt = 2 * ktp + mtbase;
        u32x4 rA0 = *(const u32x4*)(eb + srcA * ELANE + mt * 8);
        u32x4 rA1 = *(const u32x4*)(eb + srcA * ELANE + mt * 8 + 4);
        u32x4 rB0 = *(const u32x4*)(eb + srcB * ELANE + mt * 8);
        u32x4 rB1 = *(const u32x4*)(eb + srcB * ELANE + mt * 8 + 4);
        union { u32x4 v; half8 h; } c0, c1, c2, c3;
        c0.v = (u32x4){rA0[0], rA0[1], rB0[0], rB0[1]};
        c1.v = (u32x4){rA0[2], rA0[3], rB0[2], rB0[3]};
        c2.v = (u32x4){rA1[0], rA1[1], rB1[0], rB1[1]};
        c3.v = (u32x4){rA1[2], rA1[3], rB1[2], rB1[3]};
        b[0][ktp] = c0.h;
        b[1][ktp] = c1.h;
        b[2][ktp] = c2.h;
        b[3][ktp] = c3.h;
    }
}

__global__ __launch_bounds__(256) void mlp_kernel(
    const unsigned* __restrict__ feat32, const half8* __restrict__ wf,
    const float* __restrict__ wsB, float* __restrict__ out, int npts)
{
    __shared__ __align__(16) unsigned ebuf[4 * 64 * ELANE];
    const int t = threadIdx.x;
    const int lane = t & 63, wv = t >> 6;
    const int col = lane & 15, quad = lane >> 4;
    const long base = (long)blockIdx.x * 256 + wv * 64;
    unsigned* eb = ebuf + wv * (64 * ELANE);
    const int q1 = 2 * (quad & 1);
    const unsigned srcA = (unsigned)(col + 16 * q1);
    const unsigned srcB = (unsigned)(col + 16 * (q1 + 1));
    const int mtbase = quad >> 1;

    half8 b[4][4];
    #pragma unroll
    for (int nt = 0; nt < 4; nt++) {
        const long pt = base + nt * 16 + col;
        union { unsigned u4[4]; half8 v; } cv;
        #pragma unroll
        for (int jj = 0; jj < 4; jj++)
            cv.u4[jj] = feat32[(size_t)(quad * 4 + jj) * npts + pt];
        b[nt][0] = cv.v;
    }

    layer_fwd4<1, 0 >(b, wf, wsB, 0, eb, lane, quad, srcA, srcB, mtbase);  // 32->128
    layer_fwd4<4, 8 >(b, wf, wsB, 1, eb, lane, quad, srcA, srcB, mtbase);  // 128->128
    layer_fwd4<4, 40>(b, wf, wsB, 2, eb, lane, quad, srcA, srcB, mtbase);  // 128->128
    layer_fwd4<4, 72>(b, wf, wsB, 3, eb, lane, quad, srcA, srcB, mtbase);  // 128->128

    f32x4 biaso = *(const f32x4*)&wsB[512 + quad * 4];
    f32x4 acco[4] = {biaso, biaso, biaso, biaso};
    #pragma unroll
    for (int kt = 0; kt < 4; kt++) {
        half8 w = wf[(size_t)(104 + kt) * 64 + lane];
        #pragma unroll
        for (int nt = 0; nt < 4; nt++)
            acco[nt] = __builtin_amdgcn_mfma_f32_16x16x32_f16(w, b[nt][kt], acco[nt], 0, 0, 0);
    }
    if (quad == 0) {
        #pragma unroll
        for (int nt = 0; nt < 4; nt++) {
            f32x4 v;
            #pragma unroll
            for (int r = 0; r < 4; r++) v[r] = acco[nt][r] * INV_SCALE;
            *(f32x4*)(out + (base + nt * 16 + col) * 4) = v;
        }
    }
}

// ---------------------------------------------------------------------------
// Fallback path (ws too small): R1-style fused kernel, unchanged.
// ---------------------------------------------------------------------------
template<int KT, int TOFF, bool RELU>
__device__ __forceinline__ void mlp_layer(_Float16* h, const half8* __restrict__ wf,
                                          const float* __restrict__ wsB, int layerIdx,
                                          int m0, int lane)
{
    const int col = lane & 15, quad = lane >> 4;
    const int sw = (col & 3) << 3;
    half8 a[2][KT];
    #pragma unroll
    for (int mt = 0; mt < 2; mt++)
        #pragma unroll
        for (int kt = 0; kt < KT; kt++)
            a[mt][kt] = *(const half8*)&h[(m0 + mt * 16 + col) * HSTRIDE + ((kt * 32 + quad * 8) ^ sw)];
    f32x4 acc[2][8];
    #pragma unroll
    for (int nt = 0; nt < 8; nt++) {
        float bv = wsB[layerIdx * 128 + nt * 16 + col];
        acc[0][nt] = (f32x4){bv, bv, bv, bv};
        acc[1][nt] = (f32x4){bv, bv, bv, bv};
    }
    #pragma unroll
    for (int nt = 0; nt < 8; nt++) {
        half8 b[KT];
        #pragma unroll
        for (int kt = 0; kt < KT; kt++)
            b[kt] = wf[(size_t)(TOFF + nt * KT + kt) * 64 + lane];
        #pragma unroll
        for (int mt = 0; mt < 2; mt++)
            #pragma unroll
            for (int kt = 0; kt < KT; kt++)
                acc[mt][nt] = __builtin_amdgcn_mfma_f32_16x16x32_f16(a[mt][kt], b[kt], acc[mt][nt], 0, 0, 0);
    }
    #pragma unroll
    for (int mt = 0; mt < 2; mt++)
        #pragma unroll
        for (int nt = 0; nt < 8; nt++) {
            f32x4 v = acc[mt][nt];
            #pragma unroll
            for (int r = 0; r < 4; r++) {
                float x = v[r];
                if (RELU) x = fmaxf(x, 0.0f);
                h[(m0 + mt * 16 + quad * 4 + r) * HSTRIDE + ((nt * 16 + col) ^ (r << 3))] = (_Float16)x;
            }
        }
}

__global__ __launch_bounds__(256, 2) void fused_kernel(
    const float* __restrict__ pos, const float* __restrict__ bmn, const float* __restrict__ bmx,
    const float* __restrict__ tables, const half8* __restrict__ wf, const float* __restrict__ wsB,
    float* __restrict__ out)
{
    __shared__ _Float16 hbuf[128 * HSTRIDE];
    __shared__ float outstage[512];
    const int t = threadIdx.x;
    const long base = (long)blockIdx.x * 128;
    {
        const int p = t >> 1, hh = t & 1;
        const long gp = base + p;
        const float b0x = bmn[0], b0y = bmn[1], b0z = bmn[2];
        const float nx = (pos[gp * 3 + 0] - b0x) / (bmx[0] - b0x);
        const float ny = (pos[gp * 3 + 1] - b0y) / (bmx[1] - b0y);
        const float nz = (pos[gp * 3 + 2] - b0z) / (bmx[2] - b0z);
        constexpr float RLO[8] = {16.f, 20.f, 25.f, 32.f, 40.f, 50.f, 64.f, 80.f};
        constexpr float RHI[8] = {101.f, 128.f, 161.f, 203.f, 256.f, 322.f, 406.f, 512.f};
        half8 fa, fb;
        #pragma unroll
        for (int li = 0; li < 8; li++) {
            const float res = hh ? RHI[li] : RLO[li];
            const float* tbl = tables + ((size_t)(hh * 8 + li) << 20);
            float xs = nx * res, ys = ny * res, zs = nz * res;
            float fx = floorf(xs), fy = floorf(ys), fz = floorf(zs);
            unsigned xi = (unsigned)fx, yi = (unsigned)fy, zi = (unsigned)fz;
            float tx = xs - fx, ty = ys - fy, tz = zs - fz;
            unsigned hx[2] = {xi, xi + 1u};
            unsigned hy[2] = {yi * 2654435761u, (yi + 1u) * 2654435761u};
            unsigned hz[2] = {zi * 805459861u, (zi + 1u) * 805459861u};
            float wx[2] = {1.0f - tx, tx}, wy[2] = {1.0f - ty, ty}, wz[2] = {1.0f - tz, tz};
            float a0 = 0.0f, a1 = 0.0f;
            #pragma unroll
            for (int c = 0; c < 8; c++) {
                unsigned hsh = hx[c & 1] ^ hy[(c >> 1) & 1] ^ hz[c >> 2];
                unsigned idx = hsh & TMASK;
                f32x2 f = *(const f32x2*)(tbl + (size_t)idx * 2);
                float w = wx[c & 1] * wy[(c >> 1) & 1] * wz[c >> 2];
                a0 += w * f.x;
                a1 += w * f.y;
            }
            if (li < 4) { fa[2 * li]       = (_Float16)(a0 * SCALE); fa[2 * li + 1]       = (_Float16)(a1 * SCALE); }
            else        { fb[2 * (li - 4)] = (_Float16)(a0 * SCALE); fb[2 * (li - 4) + 1] = (_Float16)(a1 * SCALE); }
        }
        const int sw = (p & 3) << 3;
        *(half8*)&hbuf[p * HSTRIDE + ((hh * 16) ^ sw)]       = fa;
        *(half8*)&hbuf[p * HSTRIDE + (((hh * 16) + 8) ^ sw)] = fb;
    }
    __syncthreads();
    {
        const int lane = t & 63;
        const int m0 = (t >> 6) * 32;
        mlp_layer<1, 0,   true>(hbuf, wf, wsB, 0, m0, lane);
        mlp_layer<4, 8,   true>(hbuf, wf, wsB, 1, m0, lane);
        mlp_layer<4, 40,  true>(hbuf, wf, wsB, 2, m0, lane);
        mlp_layer<4, 72,  true>(hbuf, wf, wsB, 3, m0, lane);
        const int col = lane & 15, quad = lane >> 4;
        const int sw = (col & 3) << 3;
        half8 a[2][4];
        #pragma unroll
        for (int mt = 0; mt < 2; mt++)
            #pragma unroll
            for (int kt = 0; kt < 4; kt++)
                a[mt][kt] = *(const half8*)&hbuf[(m0 + mt * 16 + col) * HSTRIDE + ((kt * 32 + quad * 8) ^ sw)];
        float bv = wsB[512 + col];
        f32x4 acc[2] = {(f32x4){bv, bv, bv, bv}, (f32x4){bv, bv, bv, bv}};
        #pragma unroll
        for (int kt = 0; kt < 4; kt++) {
            half8 bfr = wf[(size_t)(104 + kt) * 64 + lane];
            #pragma unroll
            for (int mt = 0; mt < 2; mt++)
                acc[mt] = __builtin_amdgcn_mfma_f32_16x16x32_f16(a[mt][kt], bfr, acc[mt], 0, 0, 0);
        }
        if (col < 4) {
            #pragma unroll
            for (int mt = 0; mt < 2; mt++)
                #pragma unroll
                for (int r = 0; r < 4; r++)
                    outstage[(m0 + mt * 16 + quad * 4 + r) * 4 + col] = acc[mt][r] * INV_SCALE;
        }
    }
    __syncthreads();
    if (t < 128) {
        f32x4 v = ((const f32x4*)outstage)[t];
        *(f32x4*)(out + (base + t) * 4) = v;
    }
}

extern "C" void kernel_launch(void* const* d_in, const int* in_sizes, int n_in,
                              void* d_out, int out_size, void* d_ws, size_t ws_size,
                              hipStream_t stream) {
    const float* pos    = (const float*)d_in[0];
    const float* bmn    = (const float*)d_in[1];
    const float* bmx    = (const float*)d_in[2];
    const float* tables = (const float*)d_in[3];
    const float* W0 = (const float*)d_in[4];
    const float* b0 = (const float*)d_in[5];
    const float* W1 = (const float*)d_in[6];
    const float* b1 = (const float*)d_in[7];
    const float* W2 = (const float*)d_in[8];
    const float* b2 = (const float*)d_in[9];
    const float* W3 = (const float*)d_in[10];
    const float* b3 = (const float*)d_in[11];
    const float* Wm = (const float*)d_in[12];
    const float* bm = (const float*)d_in[13];

    const int N = in_sizes[0] / 3;
    const size_t featBytes    = (size_t)N * 16 * 4;             // [16][N] f16x2
    const size_t tabFineBytes = (size_t)8 * 524288 * 2 * 2;     // 16 MB f16, levels 8-15
    const size_t denseBytes   = ((size_t)DSLOT_TOTAL * 16 + 255) & ~(size_t)255;  // ~4.6 MB
    const size_t need = featBytes + tabFineBytes + denseBytes + 110592 + 2112;

    if (ws_size >= need && (N % 2048) == 0) {
        _Float16* feat  = (_Float16*)d_ws;
        _Float16* tabF  = (_Float16*)((char*)d_ws + featBytes);
        unsigned* dense = (unsigned*)((char*)d_ws + featBytes + tabFineBytes);
        _Float16* wsW   = (_Float16*)((char*)d_ws + featBytes + tabFineBytes + denseBytes);
        float*    wsB   = (float*)((char*)d_ws + featBytes + tabFineBytes + denseBytes + 110592);
        prep_kernel<<<8192 + 30, 256, 0, stream>>>(W0, W1, W2, W3, Wm, b0, b1, b2, b3, bm,
                                                   wsW, wsB, tables + (size_t)8 * 524288 * 2,
                                                   tabF, 8192);
        dense_build<<<(DSLOT_TOTAL * 4 + 255) / 256, 256, 0, stream>>>(tables, dense);
        encode_kernel<<<(N / 2048) * 8, 256, 0, stream>>>(pos, bmn, bmx, tabF,
                                                          (const u32x4*)dense, feat, N);
        mlp_kernel<<<N / 256, 256, 0, stream>>>((const unsigned*)feat, (const half8*)wsW,
                                                wsB, (float*)d_out, N);
    } else {
        _Float16* wsW = (_Float16*)d_ws;
        float*    wsB = (float*)((char*)d_ws + 110592);
        prep_kernel<<<30, 256, 0, stream>>>(W0, W1, W2, W3, Wm, b0, b1, b2, b3, bm,
                                            wsW, wsB, tables, (_Float16*)nullptr, 0);
        fused_kernel<<<N / 128, 256, 0, stream>>>(pos, bmn, bmx, tables,
                                                  (const half8*)wsW, wsB, (float*)d_out);
    }
}